// Round 6
// baseline (522.116 us; speedup 1.0000x reference)
//
#include <hip/hip_runtime.h>

#define S_LEN 4096
#define NH 12
#define HD 64
#define DMODEL 768
#define BATCH 2
#define MTOT (BATCH * S_LEN) /* 8192 */

typedef __bf16 bf16x8 __attribute__((ext_vector_type(8)));
typedef __bf16 bf16x4 __attribute__((ext_vector_type(4)));
typedef float f32x4 __attribute__((ext_vector_type(4)));
typedef float f32x8 __attribute__((ext_vector_type(8)));

#define SM_SCALE_LOG2E 0.18033688f /* 0.125 * log2(e), folded into Q at GEMM1 */

__device__ __forceinline__ f32x4 f32x4_zero() {
  f32x4 z = {0.f, 0.f, 0.f, 0.f};
  return z;
}

// ---------------- prep: f32 -> bf16 (vectorized) ----------------
__global__ __launch_bounds__(256) void cvt_f32_bf16(const float* __restrict__ in,
                                                    __bf16* __restrict__ out, int n8) {
  int i = blockIdx.x * 256 + threadIdx.x;
  if (i >= n8) return;
  f32x8 a = ((const f32x8*)in)[i];
  bf16x8 o;
#pragma unroll
  for (int j = 0; j < 8; ++j) o[j] = (__bf16)a[j];
  ((bf16x8*)out)[i] = o;
}

// ---------------- prep: transpose [768][N] f32 -> [N][768] bf16 ----------------
__global__ __launch_bounds__(256) void transpose_cvt(const float* __restrict__ in,
                                                     __bf16* __restrict__ out, int N) {
  __shared__ __bf16 t[64][72];  // padded
  int kb = blockIdx.x * 64, nb = blockIdx.y * 64;
  int c = threadIdx.x & 63, r0 = threadIdx.x >> 6;
#pragma unroll
  for (int i = 0; i < 16; ++i) {
    int r = r0 * 16 + i;
    t[c][r] = (__bf16)in[(size_t)(kb + r) * N + nb + c];
  }
  __syncthreads();
#pragma unroll
  for (int i = 0; i < 16; ++i) {
    int r = r0 * 16 + i;
    out[(size_t)(nb + r) * DMODEL + kb + c] = t[r][c];
  }
}

// ---------------- shared GEMM core: C[128x128] += A[128xK] * Bt[128xK]^T ----------------
__device__ __forceinline__ void gemm128_bt(const __bf16* __restrict__ A,
                                           const __bf16* __restrict__ Bt,
                                           int m0, int n0, int K,
                                           __bf16* Alds, __bf16* Blds,
                                           f32x4 acc[4][4]) {
  const int tid = threadIdx.x;
  const int l = tid & 63, w = tid >> 6;
  const int wr = w >> 1, wc = w & 1;
  const int g = l >> 4, ln = l & 15;
  for (int k0 = 0; k0 < K; k0 += 64) {
#pragma unroll
    for (int i = 0; i < 4; ++i) {
      int chunk = tid + i * 256;
      int row = chunk >> 3, cs = chunk & 7;
      int dst = row * 64 + ((cs ^ (row & 7)) << 3);
      *(bf16x8*)(Alds + dst) = *(const bf16x8*)(A + (size_t)(m0 + row) * K + k0 + cs * 8);
      *(bf16x8*)(Blds + dst) = *(const bf16x8*)(Bt + (size_t)(n0 + row) * K + k0 + cs * 8);
    }
    __syncthreads();
#pragma unroll
    for (int kk = 0; kk < 2; ++kk) {
      bf16x8 af[4], bfr[4];
#pragma unroll
      for (int mi = 0; mi < 4; ++mi) {
        int row = wr * 64 + mi * 16 + ln;
        af[mi] = *(const bf16x8*)(Alds + row * 64 + ((((kk << 2) + g) ^ (row & 7)) << 3));
      }
#pragma unroll
      for (int ni = 0; ni < 4; ++ni) {
        int row = wc * 64 + ni * 16 + ln;
        bfr[ni] = *(const bf16x8*)(Blds + row * 64 + ((((kk << 2) + g) ^ (row & 7)) << 3));
      }
#pragma unroll
      for (int mi = 0; mi < 4; ++mi)
#pragma unroll
        for (int ni = 0; ni < 4; ++ni)
          acc[mi][ni] =
              __builtin_amdgcn_mfma_f32_16x16x32_bf16(af[mi], bfr[ni], acc[mi][ni], 0, 0, 0);
    }
    __syncthreads();
  }
}

// ---------------- GEMM1: qkv = xb @ Wqkv + bqkv; Q pre-scaled by 0.125*log2e;
// scatter Q,K [B,H,S,Hd]; V transposed [B,H,Hd,S] ----------------
__global__ __launch_bounds__(256) void gemm_qkv(const __bf16* __restrict__ xb,
                                                const __bf16* __restrict__ Wt,
                                                const float* __restrict__ bqkv,
                                                __bf16* __restrict__ Qo,
                                                __bf16* __restrict__ Ko,
                                                __bf16* __restrict__ Vto) {
  __shared__ __bf16 Alds[128 * 64];
  __shared__ __bf16 Blds[128 * 64];
  int bm = blockIdx.x & 63, bn = blockIdx.x >> 6;
  int m0 = bm * 128, n0 = bn * 128;
  f32x4 acc[4][4];
#pragma unroll
  for (int i = 0; i < 4; ++i)
#pragma unroll
    for (int j = 0; j < 4; ++j) acc[i][j] = f32x4_zero();
  gemm128_bt(xb, Wt, m0, n0, DMODEL, Alds, Blds, acc);

  const int l = threadIdx.x & 63, w = threadIdx.x >> 6;
  const int wr = w >> 1, wc = w & 1, g = l >> 4, ln = l & 15;
#pragma unroll
  for (int ni = 0; ni < 4; ++ni) {
    int ncol = n0 + wc * 64 + ni * 16 + ln;
    int which = ncol / DMODEL;  // 0=q 1=k 2=v (uniform per 16-col fragment)
    int dd = ncol - which * DMODEL;
    int h = dd >> 6, hd = dd & 63;
    float bias = bqkv[ncol];
    if (which == 2) {
#pragma unroll
      for (int mi = 0; mi < 4; ++mi)
#pragma unroll
        for (int r = 0; r < 4; ++r) {
          int mrow = m0 + wr * 64 + mi * 16 + 4 * g + r;
          int b = mrow >> 12, s = mrow & (S_LEN - 1);
          float v = acc[mi][ni][r] + bias;
          Vto[(((size_t)(b * NH + h) * HD) + hd) * S_LEN + s] = (__bf16)v;
        }
    } else {
      __bf16* op = (which == 0) ? Qo : Ko;
      const float scl = (which == 0) ? SM_SCALE_LOG2E : 1.0f;
#pragma unroll
      for (int mi = 0; mi < 4; ++mi)
#pragma unroll
        for (int r = 0; r < 4; ++r) {
          int mrow = m0 + wr * 64 + mi * 16 + 4 * g + r;
          int b = mrow >> 12, s = mrow & (S_LEN - 1);
          float v = (acc[mi][ni][r] + bias) * scl;
          op[((((size_t)b * NH + h) * S_LEN) + s) * HD + hd] = (__bf16)v;
        }
    }
  }
}

// ---------------- GEMM2: out = Yb @ Wout + bout (fp32 out) ----------------
__global__ __launch_bounds__(256) void gemm_out(const __bf16* __restrict__ yb,
                                                const __bf16* __restrict__ Wt,
                                                const float* __restrict__ bout,
                                                float* __restrict__ out) {
  __shared__ __bf16 Alds[128 * 64];
  __shared__ __bf16 Blds[128 * 64];
  int bm = blockIdx.x & 63, bn = blockIdx.x >> 6;
  int m0 = bm * 128, n0 = bn * 128;
  f32x4 acc[4][4];
#pragma unroll
  for (int i = 0; i < 4; ++i)
#pragma unroll
    for (int j = 0; j < 4; ++j) acc[i][j] = f32x4_zero();
  gemm128_bt(yb, Wt, m0, n0, DMODEL, Alds, Blds, acc);

  const int l = threadIdx.x & 63, w = threadIdx.x >> 6;
  const int wr = w >> 1, wc = w & 1, g = l >> 4, ln = l & 15;
#pragma unroll
  for (int ni = 0; ni < 4; ++ni) {
    int ncol = n0 + wc * 64 + ni * 16 + ln;
    float bias = bout[ncol];
#pragma unroll
    for (int mi = 0; mi < 4; ++mi)
#pragma unroll
      for (int r = 0; r < 4; ++r) {
        int mrow = m0 + wr * 64 + mi * 16 + 4 * g + r;
        out[(size_t)mrow * DMODEL + ncol] = acc[mi][ni][r] + bias;
      }
  }
}

// ---------------- causal flash attention v6 ----------------
// Block = 4 waves = one antithetic 32-row chunk pair (127-p heavy, then p),
// processed sequentially with register reuse. Within each chunk all 4 waves
// split kv tiles t==w (mod 4): every wave in the grid does ~16.3 iterations
// (constant) -> perfect balance. Partial (O, rowsum) combined via plane-layout
// LDS reduce (exact: fixed-shift softmax partials add with no renormalization).
// Inner body = v5 verbatim (swapped QK^T, exp2 softmax — scale pre-folded into
// Q, ones-MFMA row sums, P-bounce LDS pitch 136, K/V register prefetch).
#define P_PITCH 136

__global__ __launch_bounds__(256, 4) void attn_fwd6(const __bf16* __restrict__ Q,
                                                    const __bf16* __restrict__ K,
                                                    const __bf16* __restrict__ Vt,
                                                    __bf16* __restrict__ Y) {
  __shared__ char Lsh[20480];  // P-bounce slabs (4x4352) / combine planes (5x4096), barrier-separated

  const int tid = threadIdx.x;
  const int w = tid >> 6, l = tid & 63;
  const int g = l >> 4, ln = l & 15;
  const int i = blockIdx.x;
  const int xcd = i & 7, j = i >> 3;   // j in 0..191
  const int head = xcd * 3 + (j % 3);  // 3 heads per XCD
  const int p = j / 3;                 // pair index 0..63

  const size_t hb = (size_t)head * (S_LEN * HD);
  const __bf16* Qh = Q + hb;
  const __bf16* Kh = K + hb;
  const __bf16* Vh = Vt + hb;  // [HD][S]
  const int bb = head / NH, hh = head - bb * NH;
  __bf16* Yp = Y + ((size_t)bb * S_LEN) * DMODEL + hh * HD;

  char* Pb = Lsh + w * 4352;
  char* wbA = Pb + ln * P_PITCH + 8 * g;   // + 32*jt
  char* rbA = Pb + ln * P_PITCH + 16 * g;  // + 64*ks
  char* wbB = wbA + 16 * P_PITCH;
  char* rbB = rbA + 16 * P_PITCH;
  const int sw = (ln & 7) << 4;

  bf16x8 ones;
#pragma unroll
  for (int t = 0; t < 8; ++t) ones[t] = (__bf16)1.0f;

  for (int pass = 0; pass < 2; ++pass) {
    const int c = pass ? p : 127 - p;
    const int q0A = 32 * c, q0B = q0A + 16;
    const int nT = (c + 2) >> 1;  // tiles of 64 kv covering [0, 32c+32)
    const int qA = q0A + ln, qB = q0B + ln;
    if (pass) __syncthreads();  // P slab vs previous combine reads

    bf16x8 qfA[2], qfB[2];
#pragma unroll
    for (int t = 0; t < 2; ++t) {
      qfA[t] = *(const bf16x8*)(Qh + (size_t)(q0A + ln) * HD + 32 * t + 8 * g);
      qfB[t] = *(const bf16x8*)(Qh + (size_t)(q0B + ln) * HD + 32 * t + 8 * g);
    }

    f32x4 oA[4], oB[4], o5A, o5B;
#pragma unroll
    for (int nt = 0; nt < 4; ++nt) {
      oA[nt] = f32x4_zero();
      oB[nt] = f32x4_zero();
    }
    o5A = f32x4_zero();
    o5B = f32x4_zero();

    // rolling pointers at tile t = w
    const __bf16* kp = Kh + (size_t)(64 * w + ln) * HD + 8 * g;
    const __bf16* vp = Vh + (size_t)ln * S_LEN + 64 * w + 8 * g;

    bf16x8 kf[4][2], vf[4][2];
#pragma unroll
    for (int jt = 0; jt < 4; ++jt)
#pragma unroll
      for (int t = 0; t < 2; ++t) kf[jt][t] = *(const bf16x8*)(kp + 16 * jt * HD + 32 * t);
#pragma unroll
    for (int nt = 0; nt < 4; ++nt)
#pragma unroll
      for (int ks = 0; ks < 2; ++ks)
        vf[nt][ks] = *(const bf16x8*)(vp + (size_t)16 * nt * S_LEN + 32 * ks);

    for (int t = w; t < nT; t += 4) {
      const int kv0 = t * 64;
      const bool more = (t + 4) < nT;
      const bool diag = (kv0 + 64) > q0A;

      // ---- QK^T subtile A ----
      f32x4 z[4];
      __builtin_amdgcn_s_setprio(1);
#pragma unroll
      for (int jt = 0; jt < 4; ++jt) {
        f32x4 t0 = f32x4_zero();
        t0 = __builtin_amdgcn_mfma_f32_16x16x32_bf16(kf[jt][0], qfA[0], t0, 0, 0, 0);
        z[jt] = __builtin_amdgcn_mfma_f32_16x16x32_bf16(kf[jt][1], qfA[1], t0, 0, 0, 0);
      }
      __builtin_amdgcn_s_setprio(0);

      // ---- softmax A -> LDS (z already log2-scaled) ----
      if (!diag) {
#pragma unroll
        for (int jt = 0; jt < 4; ++jt) {
          bf16x4 qd;
#pragma unroll
          for (int r = 0; r < 4; ++r) qd[r] = (__bf16)__builtin_exp2f(z[jt][r]);
          *(bf16x4*)(wbA + 32 * jt) = qd;
        }
      } else {
        const int thrA = qA - kv0;
#pragma unroll
        for (int jt = 0; jt < 4; ++jt) {
          bf16x4 qd;
#pragma unroll
          for (int r = 0; r < 4; ++r) {
            float pv = __builtin_exp2f(z[jt][r]);
            if (16 * jt + 4 * g + r > thrA) pv = 0.f;
            qd[r] = (__bf16)pv;
          }
          *(bf16x4*)(wbA + 32 * jt) = qd;
        }
      }

      // ---- QK^T subtile B (kf last use) ----
      __builtin_amdgcn_s_setprio(1);
#pragma unroll
      for (int jt = 0; jt < 4; ++jt) {
        f32x4 t0 = f32x4_zero();
        t0 = __builtin_amdgcn_mfma_f32_16x16x32_bf16(kf[jt][0], qfB[0], t0, 0, 0, 0);
        z[jt] = __builtin_amdgcn_mfma_f32_16x16x32_bf16(kf[jt][1], qfB[1], t0, 0, 0, 0);
      }
      __builtin_amdgcn_s_setprio(0);

      // ---- prefetch next K tile (t+4) into kf (WAR-safe: QK done) ----
      kp += (size_t)256 * HD;
      if (more) {
#pragma unroll
        for (int jt = 0; jt < 4; ++jt)
#pragma unroll
          for (int t2 = 0; t2 < 2; ++t2)
            kf[jt][t2] = *(const bf16x8*)(kp + 16 * jt * HD + 32 * t2);
      }

      // ---- read P_A fragments ----
      bf16x8 paA0 = *(const bf16x8*)(rbA);
      bf16x8 paA1 = *(const bf16x8*)(rbA + 64);

      // ---- softmax B -> LDS ----
      if (!diag) {
#pragma unroll
        for (int jt = 0; jt < 4; ++jt) {
          bf16x4 qd;
#pragma unroll
          for (int r = 0; r < 4; ++r) qd[r] = (__bf16)__builtin_exp2f(z[jt][r]);
          *(bf16x4*)(wbB + 32 * jt) = qd;
        }
      } else {
        const int thrB = qB - kv0;
#pragma unroll
        for (int jt = 0; jt < 4; ++jt) {
          bf16x4 qd;
#pragma unroll
          for (int r = 0; r < 4; ++r) {
            float pv = __builtin_exp2f(z[jt][r]);
            if (16 * jt + 4 * g + r > thrB) pv = 0.f;
            qd[r] = (__bf16)pv;
          }
          *(bf16x4*)(wbB + 32 * jt) = qd;
        }
      }

      // ---- PV subtile A (+ row-sum via ones) ----
      __builtin_amdgcn_s_setprio(1);
      o5A = __builtin_amdgcn_mfma_f32_16x16x32_bf16(paA0, ones, o5A, 0, 0, 0);
      o5A = __builtin_amdgcn_mfma_f32_16x16x32_bf16(paA1, ones, o5A, 0, 0, 0);
#pragma unroll
      for (int nt = 0; nt < 4; ++nt) {
        oA[nt] = __builtin_amdgcn_mfma_f32_16x16x32_bf16(paA0, vf[nt][0], oA[nt], 0, 0, 0);
        oA[nt] = __builtin_amdgcn_mfma_f32_16x16x32_bf16(paA1, vf[nt][1], oA[nt], 0, 0, 0);
      }
      __builtin_amdgcn_s_setprio(0);

      // ---- PV subtile B ----
      bf16x8 paB0 = *(const bf16x8*)(rbB);
      bf16x8 paB1 = *(const bf16x8*)(rbB + 64);
      __builtin_amdgcn_s_setprio(1);
      o5B = __builtin_amdgcn_mfma_f32_16x16x32_bf16(paB0, ones, o5B, 0, 0, 0);
      o5B = __builtin_amdgcn_mfma_f32_16x16x32_bf16(paB1, ones, o5B, 0, 0, 0);
#pragma unroll
      for (int nt = 0; nt < 4; ++nt) {
        oB[nt] = __builtin_amdgcn_mfma_f32_16x16x32_bf16(paB0, vf[nt][0], oB[nt], 0, 0, 0);
        oB[nt] = __builtin_amdgcn_mfma_f32_16x16x32_bf16(paB1, vf[nt][1], oB[nt], 0, 0, 0);
      }
      __builtin_amdgcn_s_setprio(0);

      // ---- prefetch next V tile (t+4) into vf (WAR-safe: PV done) ----
      vp += 256;
      if (more) {
#pragma unroll
        for (int nt = 0; nt < 4; ++nt)
#pragma unroll
          for (int ks = 0; ks < 2; ++ks)
            vf[nt][ks] = *(const bf16x8*)(vp + (size_t)16 * nt * S_LEN + 32 * ks);
      }
    }

    // ---- combine across 4 waves (plane layout: plane j at j*4096, wave slab
    // w2 at w2*1024, lane at l*16 -> contiguous 16B/lane, conflict-free) ----
#pragma unroll
    for (int half = 0; half < 2; ++half) {
      __syncthreads();
      {
        char* cb = Lsh + w * 1024 + l * 16;
        *(f32x4*)(cb + 0 * 4096) = half ? oB[0] : oA[0];
        *(f32x4*)(cb + 1 * 4096) = half ? oB[1] : oA[1];
        *(f32x4*)(cb + 2 * 4096) = half ? oB[2] : oA[2];
        *(f32x4*)(cb + 3 * 4096) = half ? oB[3] : oA[3];
        *(f32x4*)(cb + 4 * 4096) = half ? o5B : o5A;
      }
      __syncthreads();
      {
        // wave w reduces output columns d = 16w + ln
        f32x4 ov = f32x4_zero(), sv = f32x4_zero();
#pragma unroll
        for (int w2 = 0; w2 < 4; ++w2) {
          ov += *(const f32x4*)(Lsh + w * 4096 + w2 * 1024 + l * 16);
          sv += *(const f32x4*)(Lsh + 4 * 4096 + w2 * 1024 + l * 16);
        }
        const int q0X = half ? q0B : q0A;
#pragma unroll
        for (int r = 0; r < 4; ++r)
          Yp[(size_t)(q0X + 4 * g + r) * DMODEL + 16 * w + ln] = (__bf16)(ov[r] / sv[r]);
      }
    }
  }
}

extern "C" void kernel_launch(void* const* d_in, const int* in_sizes, int n_in,
                              void* d_out, int out_size, void* d_ws, size_t ws_size,
                              hipStream_t stream) {
  const float* x = (const float*)d_in[0];
  const float* Wqkv = (const float*)d_in[1];
  const float* bqkv = (const float*)d_in[2];
  const float* Wout = (const float*)d_in[3];
  const float* bout = (const float*)d_in[4];
  float* out = (float*)d_out;

  char* ws = (char*)d_ws;
  size_t off = 0;
  auto take = [&](size_t bytes) {
    char* p = ws + off;
    off += bytes;
    return p;
  };
  const size_t MD2 = (size_t)MTOT * DMODEL * 2;
  __bf16* xb = (__bf16*)take(MD2);
  __bf16* Wqkv_t = (__bf16*)take((size_t)3 * DMODEL * DMODEL * 2);
  __bf16* Wout_t = (__bf16*)take((size_t)DMODEL * DMODEL * 2);
  __bf16* Qb = (__bf16*)take(MD2);
  __bf16* Kb = (__bf16*)take(MD2);
  __bf16* Vtb = (__bf16*)take(MD2);
  __bf16* Yb = (__bf16*)take(MD2);

  int n8 = MTOT * DMODEL / 8;
  cvt_f32_bf16<<<(n8 + 255) / 256, 256, 0, stream>>>(x, xb, n8);
  transpose_cvt<<<dim3(DMODEL / 64, 3 * DMODEL / 64), 256, 0, stream>>>(Wqkv, Wqkv_t, 3 * DMODEL);
  transpose_cvt<<<dim3(DMODEL / 64, DMODEL / 64), 256, 0, stream>>>(Wout, Wout_t, DMODEL);
  gemm_qkv<<<64 * (3 * DMODEL / 128), 256, 0, stream>>>(xb, Wqkv_t, bqkv, Qb, Kb, Vtb);
  attn_fwd6<<<1536, 256, 0, stream>>>(Qb, Kb, Vtb, Yb);
  gemm_out<<<64 * (DMODEL / 128), 256, 0, stream>>>(Yb, Wout_t, bout, out);
}

// Round 7
// 282.209 us; speedup vs baseline: 1.8501x; 1.8501x over previous
//
#include <hip/hip_runtime.h>

#define S_LEN 4096
#define NH 12
#define HD 64
#define DMODEL 768
#define BATCH 2
#define MTOT (BATCH * S_LEN) /* 8192 */

typedef __bf16 bf16x8 __attribute__((ext_vector_type(8)));
typedef __bf16 bf16x4 __attribute__((ext_vector_type(4)));
typedef float f32x4 __attribute__((ext_vector_type(4)));
typedef float f32x8 __attribute__((ext_vector_type(8)));

#define SM_SCALE_LOG2E 0.18033688f /* 0.125 * log2(e), folded into Q at GEMM1 */
#define SLAB_STRIDE 4224           /* 32x64 bf16 O (4096) + 32 f32 rowsum (128) */

__device__ __forceinline__ f32x4 f32x4_zero() {
  f32x4 z = {0.f, 0.f, 0.f, 0.f};
  return z;
}

// ---------------- prep: f32 -> bf16 (vectorized) ----------------
__global__ __launch_bounds__(256) void cvt_f32_bf16(const float* __restrict__ in,
                                                    __bf16* __restrict__ out, int n8) {
  int i = blockIdx.x * 256 + threadIdx.x;
  if (i >= n8) return;
  f32x8 a = ((const f32x8*)in)[i];
  bf16x8 o;
#pragma unroll
  for (int j = 0; j < 8; ++j) o[j] = (__bf16)a[j];
  ((bf16x8*)out)[i] = o;
}

// ---------------- prep: transpose [768][N] f32 -> [N][768] bf16 ----------------
__global__ __launch_bounds__(256) void transpose_cvt(const float* __restrict__ in,
                                                     __bf16* __restrict__ out, int N) {
  __shared__ __bf16 t[64][72];  // padded
  int kb = blockIdx.x * 64, nb = blockIdx.y * 64;
  int c = threadIdx.x & 63, r0 = threadIdx.x >> 6;
#pragma unroll
  for (int i = 0; i < 16; ++i) {
    int r = r0 * 16 + i;
    t[c][r] = (__bf16)in[(size_t)(kb + r) * N + nb + c];
  }
  __syncthreads();
#pragma unroll
  for (int i = 0; i < 16; ++i) {
    int r = r0 * 16 + i;
    out[(size_t)(nb + r) * DMODEL + kb + c] = t[r][c];
  }
}

// ---------------- shared GEMM core: C[128x128] += A[128xK] * Bt[128xK]^T ----------------
__device__ __forceinline__ void gemm128_bt(const __bf16* __restrict__ A,
                                           const __bf16* __restrict__ Bt,
                                           int m0, int n0, int K,
                                           __bf16* Alds, __bf16* Blds,
                                           f32x4 acc[4][4]) {
  const int tid = threadIdx.x;
  const int l = tid & 63, w = tid >> 6;
  const int wr = w >> 1, wc = w & 1;
  const int g = l >> 4, ln = l & 15;
  for (int k0 = 0; k0 < K; k0 += 64) {
#pragma unroll
    for (int i = 0; i < 4; ++i) {
      int chunk = tid + i * 256;
      int row = chunk >> 3, cs = chunk & 7;
      int dst = row * 64 + ((cs ^ (row & 7)) << 3);
      *(bf16x8*)(Alds + dst) = *(const bf16x8*)(A + (size_t)(m0 + row) * K + k0 + cs * 8);
      *(bf16x8*)(Blds + dst) = *(const bf16x8*)(Bt + (size_t)(n0 + row) * K + k0 + cs * 8);
    }
    __syncthreads();
#pragma unroll
    for (int kk = 0; kk < 2; ++kk) {
      bf16x8 af[4], bfr[4];
#pragma unroll
      for (int mi = 0; mi < 4; ++mi) {
        int row = wr * 64 + mi * 16 + ln;
        af[mi] = *(const bf16x8*)(Alds + row * 64 + ((((kk << 2) + g) ^ (row & 7)) << 3));
      }
#pragma unroll
      for (int ni = 0; ni < 4; ++ni) {
        int row = wc * 64 + ni * 16 + ln;
        bfr[ni] = *(const bf16x8*)(Blds + row * 64 + ((((kk << 2) + g) ^ (row & 7)) << 3));
      }
#pragma unroll
      for (int mi = 0; mi < 4; ++mi)
#pragma unroll
        for (int ni = 0; ni < 4; ++ni)
          acc[mi][ni] =
              __builtin_amdgcn_mfma_f32_16x16x32_bf16(af[mi], bfr[ni], acc[mi][ni], 0, 0, 0);
    }
    __syncthreads();
  }
}

// ---------------- GEMM1: qkv = xb @ Wqkv + bqkv; Q pre-scaled by 0.125*log2e;
// scatter Q,K [B,H,S,Hd]; V transposed [B,H,Hd,S] ----------------
__global__ __launch_bounds__(256) void gemm_qkv(const __bf16* __restrict__ xb,
                                                const __bf16* __restrict__ Wt,
                                                const float* __restrict__ bqkv,
                                                __bf16* __restrict__ Qo,
                                                __bf16* __restrict__ Ko,
                                                __bf16* __restrict__ Vto) {
  __shared__ __bf16 Alds[128 * 64];
  __shared__ __bf16 Blds[128 * 64];
  int bm = blockIdx.x & 63, bn = blockIdx.x >> 6;
  int m0 = bm * 128, n0 = bn * 128;
  f32x4 acc[4][4];
#pragma unroll
  for (int i = 0; i < 4; ++i)
#pragma unroll
    for (int j = 0; j < 4; ++j) acc[i][j] = f32x4_zero();
  gemm128_bt(xb, Wt, m0, n0, DMODEL, Alds, Blds, acc);

  const int l = threadIdx.x & 63, w = threadIdx.x >> 6;
  const int wr = w >> 1, wc = w & 1, g = l >> 4, ln = l & 15;
#pragma unroll
  for (int ni = 0; ni < 4; ++ni) {
    int ncol = n0 + wc * 64 + ni * 16 + ln;
    int which = ncol / DMODEL;  // 0=q 1=k 2=v (uniform per 16-col fragment)
    int dd = ncol - which * DMODEL;
    int h = dd >> 6, hd = dd & 63;
    float bias = bqkv[ncol];
    if (which == 2) {
#pragma unroll
      for (int mi = 0; mi < 4; ++mi)
#pragma unroll
        for (int r = 0; r < 4; ++r) {
          int mrow = m0 + wr * 64 + mi * 16 + 4 * g + r;
          int b = mrow >> 12, s = mrow & (S_LEN - 1);
          float v = acc[mi][ni][r] + bias;
          Vto[(((size_t)(b * NH + h) * HD) + hd) * S_LEN + s] = (__bf16)v;
        }
    } else {
      __bf16* op = (which == 0) ? Qo : Ko;
      const float scl = (which == 0) ? SM_SCALE_LOG2E : 1.0f;
#pragma unroll
      for (int mi = 0; mi < 4; ++mi)
#pragma unroll
        for (int r = 0; r < 4; ++r) {
          int mrow = m0 + wr * 64 + mi * 16 + 4 * g + r;
          int b = mrow >> 12, s = mrow & (S_LEN - 1);
          float v = (acc[mi][ni][r] + bias) * scl;
          op[((((size_t)b * NH + h) * S_LEN) + s) * HD + hd] = (__bf16)v;
        }
    }
  }
}

// ---------------- GEMM2: out = Yb @ Wout + bout (fp32 out) ----------------
__global__ __launch_bounds__(256) void gemm_out(const __bf16* __restrict__ yb,
                                                const __bf16* __restrict__ Wt,
                                                const float* __restrict__ bout,
                                                float* __restrict__ out) {
  __shared__ __bf16 Alds[128 * 64];
  __shared__ __bf16 Blds[128 * 64];
  int bm = blockIdx.x & 63, bn = blockIdx.x >> 6;
  int m0 = bm * 128, n0 = bn * 128;
  f32x4 acc[4][4];
#pragma unroll
  for (int i = 0; i < 4; ++i)
#pragma unroll
    for (int j = 0; j < 4; ++j) acc[i][j] = f32x4_zero();
  gemm128_bt(yb, Wt, m0, n0, DMODEL, Alds, Blds, acc);

  const int l = threadIdx.x & 63, w = threadIdx.x >> 6;
  const int wr = w >> 1, wc = w & 1, g = l >> 4, ln = l & 15;
#pragma unroll
  for (int ni = 0; ni < 4; ++ni) {
    int ncol = n0 + wc * 64 + ni * 16 + ln;
    float bias = bout[ncol];
#pragma unroll
    for (int mi = 0; mi < 4; ++mi)
#pragma unroll
      for (int r = 0; r < 4; ++r) {
        int mrow = m0 + wr * 64 + mi * 16 + 4 * g + r;
        out[(size_t)mrow * DMODEL + ncol] = acc[mi][ni][r] + bias;
      }
  }
}

// ---------------- causal flash attention v7 ----------------
// v5's verified no-spill inner loop, unchanged. New: work-unit decomposition.
// Unit = (head, 32-row chunk c, kv-part). Chunks c>=64 split into two kv
// halves handled by different blocks writing partial (bf16 O, f32 rowsum)
// slabs (exact: fixed-shift softmax partials add with no renormalization);
// chunks c<64 write Y directly. 4608 one-wave units, all <=32 iters,
// heavy-first dispatch, XCD head affinity. attn_combine merges split chunks.
#define P_PITCH 136

__global__ __launch_bounds__(64) void attn_fwd7(const __bf16* __restrict__ Q,
                                                const __bf16* __restrict__ K,
                                                const __bf16* __restrict__ Vt,
                                                __bf16* __restrict__ Y,
                                                char* __restrict__ Po) {
  __shared__ char Plds[2 * 16 * P_PITCH];  // 2 subtiles x [16 q][64 kv] pitch 136B

  const int l = threadIdx.x & 63;
  const int g = l >> 4, ln = l & 15;
  const int u = blockIdx.x;
  const int xcd = u & 7, v = u >> 3;   // v in 0..575
  const int head = xcd * 3 + (v % 3);  // 3 heads per XCD
  const int r_ = v / 3;                // rank 0..191, heavy-first

  int c, tstart, tend, part;
  bool split;
  if (r_ < 128) {  // split chunks c=127..64, two kv halves each
    c = 127 - (r_ >> 1);
    part = r_ & 1;
    int T = (c + 2) >> 1;  // ceil((32c+32)/64) kv tiles
    int h = (T + 1) >> 1;
    tstart = part ? h : 0;
    tend = part ? T : h;
    split = true;
  } else {  // direct chunks c=63..0
    c = 191 - r_;
    part = 0;
    tstart = 0;
    tend = (c + 2) >> 1;
    split = false;
  }
  const int q0A = 32 * c, q0B = q0A + 16;

  const size_t hb = (size_t)head * (S_LEN * HD);
  const __bf16* Qh = Q + hb;
  const __bf16* Vh = Vt + hb;  // [HD][S]

  char* wbA = Plds + ln * P_PITCH + 8 * g;   // + 32*jt
  char* rbA = Plds + ln * P_PITCH + 16 * g;  // + 64*ks
  char* wbB = wbA + 16 * P_PITCH;
  char* rbB = rbA + 16 * P_PITCH;

  // rolling source pointers at tile tstart
  const __bf16* kp = K + hb + (size_t)(64 * tstart + ln) * HD + 8 * g;
  const __bf16* vp = Vh + (size_t)ln * S_LEN + 64 * tstart + 8 * g;

  bf16x8 qfA[2], qfB[2];
#pragma unroll
  for (int t = 0; t < 2; ++t) {
    qfA[t] = *(const bf16x8*)(Qh + (size_t)(q0A + ln) * HD + 32 * t + 8 * g);
    qfB[t] = *(const bf16x8*)(Qh + (size_t)(q0B + ln) * HD + 32 * t + 8 * g);
  }

  bf16x8 ones;
#pragma unroll
  for (int t = 0; t < 8; ++t) ones[t] = (__bf16)1.0f;

  f32x4 oA[4], oB[4], o5A, o5B;
#pragma unroll
  for (int nt = 0; nt < 4; ++nt) {
    oA[nt] = f32x4_zero();
    oB[nt] = f32x4_zero();
  }
  o5A = f32x4_zero();
  o5B = f32x4_zero();

  // prologue: K,V fragments for first tile
  bf16x8 kf[4][2], vf[4][2];
#pragma unroll
  for (int jt = 0; jt < 4; ++jt)
#pragma unroll
    for (int t = 0; t < 2; ++t) kf[jt][t] = *(const bf16x8*)(kp + 16 * jt * HD + 32 * t);
#pragma unroll
  for (int nt = 0; nt < 4; ++nt)
#pragma unroll
    for (int ks = 0; ks < 2; ++ks)
      vf[nt][ks] = *(const bf16x8*)(vp + (size_t)16 * nt * S_LEN + 32 * ks);

  for (int t = tstart; t < tend; ++t) {
    const int kv0 = t * 64;
    const bool more = (t + 1) < tend;
    const bool diag = (kv0 + 64) > q0A;

    // ---- QK^T subtile A ----
    f32x4 z[4];
    __builtin_amdgcn_s_setprio(1);
#pragma unroll
    for (int jt = 0; jt < 4; ++jt) {
      f32x4 t0 = f32x4_zero();
      t0 = __builtin_amdgcn_mfma_f32_16x16x32_bf16(kf[jt][0], qfA[0], t0, 0, 0, 0);
      z[jt] = __builtin_amdgcn_mfma_f32_16x16x32_bf16(kf[jt][1], qfA[1], t0, 0, 0, 0);
    }
    __builtin_amdgcn_s_setprio(0);

    // ---- softmax A -> LDS (z already log2-scaled via Q prescale) ----
    if (!diag) {
#pragma unroll
      for (int jt = 0; jt < 4; ++jt) {
        bf16x4 qd;
#pragma unroll
        for (int r = 0; r < 4; ++r) qd[r] = (__bf16)__builtin_exp2f(z[jt][r]);
        *(bf16x4*)(wbA + 32 * jt) = qd;
      }
    } else {
      const int thrA = q0A + ln - kv0;
#pragma unroll
      for (int jt = 0; jt < 4; ++jt) {
        bf16x4 qd;
#pragma unroll
        for (int r = 0; r < 4; ++r) {
          float pv = __builtin_exp2f(z[jt][r]);
          if (16 * jt + 4 * g + r > thrA) pv = 0.f;
          qd[r] = (__bf16)pv;
        }
        *(bf16x4*)(wbA + 32 * jt) = qd;
      }
    }

    // ---- QK^T subtile B (kf last use) ----
    __builtin_amdgcn_s_setprio(1);
#pragma unroll
    for (int jt = 0; jt < 4; ++jt) {
      f32x4 t0 = f32x4_zero();
      t0 = __builtin_amdgcn_mfma_f32_16x16x32_bf16(kf[jt][0], qfB[0], t0, 0, 0, 0);
      z[jt] = __builtin_amdgcn_mfma_f32_16x16x32_bf16(kf[jt][1], qfB[1], t0, 0, 0, 0);
    }
    __builtin_amdgcn_s_setprio(0);

    // ---- prefetch next K tile into kf (WAR-safe: QK done) ----
    kp += (size_t)64 * HD;
    if (more) {
#pragma unroll
      for (int jt = 0; jt < 4; ++jt)
#pragma unroll
        for (int t2 = 0; t2 < 2; ++t2)
          kf[jt][t2] = *(const bf16x8*)(kp + 16 * jt * HD + 32 * t2);
    }

    // ---- read P_A fragments ----
    bf16x8 paA0 = *(const bf16x8*)(rbA);
    bf16x8 paA1 = *(const bf16x8*)(rbA + 64);

    // ---- softmax B -> LDS ----
    if (!diag) {
#pragma unroll
      for (int jt = 0; jt < 4; ++jt) {
        bf16x4 qd;
#pragma unroll
        for (int r = 0; r < 4; ++r) qd[r] = (__bf16)__builtin_exp2f(z[jt][r]);
        *(bf16x4*)(wbB + 32 * jt) = qd;
      }
    } else {
      const int thrB = q0B + ln - kv0;
#pragma unroll
      for (int jt = 0; jt < 4; ++jt) {
        bf16x4 qd;
#pragma unroll
        for (int r = 0; r < 4; ++r) {
          float pv = __builtin_exp2f(z[jt][r]);
          if (16 * jt + 4 * g + r > thrB) pv = 0.f;
          qd[r] = (__bf16)pv;
        }
        *(bf16x4*)(wbB + 32 * jt) = qd;
      }
    }

    // ---- PV subtile A (+ row-sum via ones) ----
    __builtin_amdgcn_s_setprio(1);
    o5A = __builtin_amdgcn_mfma_f32_16x16x32_bf16(paA0, ones, o5A, 0, 0, 0);
    o5A = __builtin_amdgcn_mfma_f32_16x16x32_bf16(paA1, ones, o5A, 0, 0, 0);
#pragma unroll
    for (int nt = 0; nt < 4; ++nt) {
      oA[nt] = __builtin_amdgcn_mfma_f32_16x16x32_bf16(paA0, vf[nt][0], oA[nt], 0, 0, 0);
      oA[nt] = __builtin_amdgcn_mfma_f32_16x16x32_bf16(paA1, vf[nt][1], oA[nt], 0, 0, 0);
    }
    __builtin_amdgcn_s_setprio(0);

    // ---- PV subtile B ----
    bf16x8 paB0 = *(const bf16x8*)(rbB);
    bf16x8 paB1 = *(const bf16x8*)(rbB + 64);
    __builtin_amdgcn_s_setprio(1);
    o5B = __builtin_amdgcn_mfma_f32_16x16x32_bf16(paB0, ones, o5B, 0, 0, 0);
    o5B = __builtin_amdgcn_mfma_f32_16x16x32_bf16(paB1, ones, o5B, 0, 0, 0);
#pragma unroll
    for (int nt = 0; nt < 4; ++nt) {
      oB[nt] = __builtin_amdgcn_mfma_f32_16x16x32_bf16(paB0, vf[nt][0], oB[nt], 0, 0, 0);
      oB[nt] = __builtin_amdgcn_mfma_f32_16x16x32_bf16(paB1, vf[nt][1], oB[nt], 0, 0, 0);
    }
    __builtin_amdgcn_s_setprio(0);

    // ---- prefetch next V tile into vf (WAR-safe: PV done) ----
    vp += 64;
    if (more) {
#pragma unroll
      for (int nt = 0; nt < 4; ++nt)
#pragma unroll
        for (int ks = 0; ks < 2; ++ks)
          vf[nt][ks] = *(const bf16x8*)(vp + (size_t)16 * nt * S_LEN + 32 * ks);
    }
  }

  if (!split) {
    // direct write Y: lane holds O[q=4g+r][d=16nt+ln]
    const int bb = head / NH, hh = head - bb * NH;
    __bf16* Yp = Y + ((size_t)bb * S_LEN) * DMODEL + hh * HD;
#pragma unroll
    for (int r = 0; r < 4; ++r) {
      float lA = 1.0f / o5A[r];
      float lB = 1.0f / o5B[r];
      int qrA = q0A + 4 * g + r, qrB = q0B + 4 * g + r;
#pragma unroll
      for (int nt = 0; nt < 4; ++nt) {
        Yp[(size_t)qrA * DMODEL + 16 * nt + ln] = (__bf16)(oA[nt][r] * lA);
        Yp[(size_t)qrB * DMODEL + 16 * nt + ln] = (__bf16)(oB[nt][r] * lB);
      }
    }
  } else {
    // partial slab: O bf16 [32 rows][64 d] + rowsum f32 [32]
    char* slab = Po + (size_t)(((head << 6) + (c - 64)) * 2 + part) * SLAB_STRIDE;
#pragma unroll
    for (int r = 0; r < 4; ++r) {
      int rowA = 4 * g + r, rowB = 16 + rowA;
#pragma unroll
      for (int nt = 0; nt < 4; ++nt) {
        *(__bf16*)(slab + (rowA * 64 + 16 * nt + ln) * 2) = (__bf16)oA[nt][r];
        *(__bf16*)(slab + (rowB * 64 + 16 * nt + ln) * 2) = (__bf16)oB[nt][r];
      }
      if (ln == 0) {
        *(float*)(slab + 4096 + rowA * 4) = o5A[r];
        *(float*)(slab + 4096 + rowB * 4) = o5B[r];
      }
    }
  }
}

// ---------------- combine split-chunk partials ----------------
__global__ __launch_bounds__(256) void attn_combine(const char* __restrict__ Po,
                                                    __bf16* __restrict__ Y) {
  const int blk = blockIdx.x;  // 0..1535 = (head, c-64)
  const int head = blk >> 6, cc = blk & 63, c = cc + 64;
  const char* s0 = Po + (size_t)(((head << 6) + cc) * 2) * SLAB_STRIDE;
  const char* s1 = s0 + SLAB_STRIDE;
  const int tid = threadIdx.x;
  const int row = tid >> 3, d0 = (tid & 7) * 8;

  bf16x8 a = *(const bf16x8*)(s0 + (row * 64 + d0) * 2);
  bf16x8 b = *(const bf16x8*)(s1 + (row * 64 + d0) * 2);
  float rs = *(const float*)(s0 + 4096 + row * 4) + *(const float*)(s1 + 4096 + row * 4);
  float inv = 1.0f / rs;

  const int bb = head / NH, hh = head - bb * NH;
  __bf16* yp = Y + ((size_t)bb * S_LEN + 32 * c + row) * DMODEL + hh * HD + d0;
  bf16x8 o;
#pragma unroll
  for (int j = 0; j < 8; ++j) o[j] = (__bf16)(((float)a[j] + (float)b[j]) * inv);
  *(bf16x8*)yp = o;
}

extern "C" void kernel_launch(void* const* d_in, const int* in_sizes, int n_in,
                              void* d_out, int out_size, void* d_ws, size_t ws_size,
                              hipStream_t stream) {
  const float* x = (const float*)d_in[0];
  const float* Wqkv = (const float*)d_in[1];
  const float* bqkv = (const float*)d_in[2];
  const float* Wout = (const float*)d_in[3];
  const float* bout = (const float*)d_in[4];
  float* out = (float*)d_out;

  char* ws = (char*)d_ws;
  size_t off = 0;
  auto take = [&](size_t bytes) {
    char* p = ws + off;
    off += bytes;
    return p;
  };
  const size_t MD2 = (size_t)MTOT * DMODEL * 2;
  __bf16* xb = (__bf16*)take(MD2);
  __bf16* Wqkv_t = (__bf16*)take((size_t)3 * DMODEL * DMODEL * 2);
  __bf16* Wout_t = (__bf16*)take((size_t)DMODEL * DMODEL * 2);
  __bf16* Qb = (__bf16*)take(MD2);
  __bf16* Kb = (__bf16*)take(MD2);
  __bf16* Vtb = (__bf16*)take(MD2);
  __bf16* Yb = (__bf16*)take(MD2);
  char* Po = take((size_t)3072 * SLAB_STRIDE);  // 24 heads x 64 chunks x 2 parts

  int n8 = MTOT * DMODEL / 8;
  cvt_f32_bf16<<<(n8 + 255) / 256, 256, 0, stream>>>(x, xb, n8);
  transpose_cvt<<<dim3(DMODEL / 64, 3 * DMODEL / 64), 256, 0, stream>>>(Wqkv, Wqkv_t, 3 * DMODEL);
  transpose_cvt<<<dim3(DMODEL / 64, DMODEL / 64), 256, 0, stream>>>(Wout, Wout_t, DMODEL);
  gemm_qkv<<<64 * (3 * DMODEL / 128), 256, 0, stream>>>(xb, Wqkv_t, bqkv, Qb, Kb, Vtb);
  attn_fwd7<<<4608, 64, 0, stream>>>(Qb, Kb, Vtb, Yb, Po);
  attn_combine<<<1536, 256, 0, stream>>>(Po, Yb);
  gemm_out<<<64 * (DMODEL / 128), 256, 0, stream>>>(Yb, Wout_t, bout, out);
}